// Round 8
// baseline (365.613 us; speedup 1.0000x reference)
//
#include <hip/hip_runtime.h>
#include <math.h>

#define IN_DIM 128
#define H1 64
#define H2 32
#define NC 8
#define SCAN_CH 1024   // elements per scan block (256 threads x 4)
#define NB_MAX 512     // max buckets (n <= 131072)
#define BLK 512        // edge partition blocks
#define CAP 10240      // LDS staging capacity per bucket (entries; max bucket ~8.6K)

typedef unsigned int u32;

__device__ __forceinline__ float bf_lo(u32 u) { return __uint_as_float(u << 16); }
__device__ __forceinline__ float bf_hi(u32 u) { return __uint_as_float(u & 0xffff0000u); }
__device__ __forceinline__ unsigned short f2b(float f) {  // RNE float->bf16
  u32 u = __float_as_uint(f);
  u += 0x7fffu + ((u >> 16) & 1u);
  return (unsigned short)(u >> 16);
}

// ---------------- P1: per-block bucket histogram (LDS atomics only) ----------------
// bucket(d) = d >> 8 (256 nodes per bucket).

__global__ __launch_bounds__(256) void k_hist(const int* __restrict__ dst,
                                              int* __restrict__ bh,
                                              int E, int EPB, int NBk) {
  __shared__ int h[NB_MAX];
  int k = blockIdx.x, tid = threadIdx.x;
  for (int i = tid; i < NBk; i += 256) h[i] = 0;
  __syncthreads();
  int st = k * EPB, en = min(E, st + EPB);
  for (int i = st + tid; i < en; i += 256)
    atomicAdd(&h[((u32)dst[i]) >> 8], 1);
  __syncthreads();
  for (int b = tid; b < NBk; b += 256) bh[b * BLK + k] = h[b];
}

// ---- generic 3-phase exclusive scan of A[L] -> S[L], S[L] = total ----

__global__ __launch_bounds__(256) void k_gsc1(const int* __restrict__ A,
                                              int* __restrict__ bsum, int L) {
  int b = blockIdx.x, tid = threadIdx.x;
  int i0 = b * SCAN_CH + tid * 4;
  int s = 0;
  if (i0 + 3 < L) {
    int4 v = *(const int4*)(A + i0);
    s = v.x + v.y + v.z + v.w;
  } else {
    for (int i = i0; i < L; ++i) s += A[i];
  }
  __shared__ int red[256];
  red[tid] = s;
  __syncthreads();
  for (int d = 128; d > 0; d >>= 1) {
    if (tid < d) red[tid] += red[tid + d];
    __syncthreads();
  }
  if (tid == 0) bsum[b] = red[0];
}

__global__ __launch_bounds__(256) void k_gsc2(const int* __restrict__ bsum,
                                              int* __restrict__ bbase,
                                              int* __restrict__ S, int nbk, int L) {
  __shared__ int part[256];
  int tid = threadIdx.x;
  int chunk = (nbk + 255) / 256;
  int st = tid * chunk, en = min(st + chunk, nbk);
  int s = 0;
  for (int i = st; i < en; ++i) s += bsum[i];
  part[tid] = s;
  __syncthreads();
  for (int d = 1; d < 256; d <<= 1) {
    int t = (tid >= d) ? part[tid - d] : 0;
    __syncthreads();
    part[tid] += t;
    __syncthreads();
  }
  int base = (tid == 0) ? 0 : part[tid - 1];
  for (int i = st; i < en; ++i) { bbase[i] = base; base += bsum[i]; }
  if (tid == 255) S[L] = part[255];
}

__global__ __launch_bounds__(256) void k_gsc3(const int* __restrict__ A,
                                              const int* __restrict__ bbase,
                                              int* __restrict__ S, int L) {
  int b = blockIdx.x, tid = threadIdx.x;
  int i0 = b * SCAN_CH + tid * 4;
  int e0 = 0, e1 = 0, e2 = 0, e3 = 0;
  if (i0 + 3 < L) {
    int4 v = *(const int4*)(A + i0);
    e0 = v.x; e1 = v.y; e2 = v.z; e3 = v.w;
  } else {
    if (i0 + 0 < L) e0 = A[i0 + 0];
    if (i0 + 1 < L) e1 = A[i0 + 1];
    if (i0 + 2 < L) e2 = A[i0 + 2];
    if (i0 + 3 < L) e3 = A[i0 + 3];
  }
  __shared__ int part[256];
  part[tid] = e0 + e1 + e2 + e3;
  __syncthreads();
  for (int d = 1; d < 256; d <<= 1) {
    int t = (tid >= d) ? part[tid - d] : 0;
    __syncthreads();
    part[tid] += t;
    __syncthreads();
  }
  int base = bbase[b] + ((tid == 0) ? 0 : part[tid - 1]);
  int o0 = base, o1 = o0 + e0, o2 = o1 + e1, o3 = o2 + e2;
  if (i0 + 3 < L) {
    int4 o; o.x = o0; o.y = o1; o.z = o2; o.w = o3;
    *(int4*)(S + i0) = o;
  } else {
    if (i0 + 0 < L) S[i0 + 0] = o0;
    if (i0 + 1 < L) S[i0 + 1] = o1;
    if (i0 + 2 < L) S[i0 + 2] = o2;
    if (i0 + 3 < L) S[i0 + 3] = o3;
  }
}

// ---------------- P3: bucket scatter (LDS cursors, disjoint global ranges) ----------------
// packed entry: bits[0,17) = src, bits[17,25) = local node id within bucket.

__global__ __launch_bounds__(256) void k_scatter(const int* __restrict__ src,
                                                 const int* __restrict__ dst,
                                                 const int* __restrict__ S,
                                                 u32* __restrict__ packed,
                                                 int E, int EPB, int NBk) {
  __shared__ int cur[NB_MAX];
  int k = blockIdx.x, tid = threadIdx.x;
  for (int b = tid; b < NBk; b += 256) cur[b] = S[b * BLK + k];
  __syncthreads();
  int st = k * EPB, en = min(E, st + EPB);
  for (int i = st + tid; i < en; i += 256) {
    int d = dst[i];
    int b = ((u32)d) >> 8;
    int pos = atomicAdd(&cur[b], 1);
    packed[pos] = (((u32)d & 255u) << 17) | (u32)src[i];
  }
}

// ---------------- P4 (R21): per-bucket sort by (dst_local, src-tile) + off + dinv ----------------
// key = dl*8 | (src>>14): each node's edges contiguous (standard CSR via off[n+1])
// AND coarse-ascending in src within the segment (8 tiles of 16K rows). This
// gives the register-accumulating sweep kernels a chip-wide src window.

__global__ __launch_bounds__(256) void k_build3(const u32* __restrict__ packed,
                                                const int* __restrict__ S,
                                                u32* __restrict__ csr2,
                                                int* __restrict__ off,
                                                float* __restrict__ dinv,
                                                int n, int NBk) {
  __shared__ int bins[2048];
  __shared__ int cur[2048];
  __shared__ int scn[256];
  __shared__ u32 sbuf[CAP];  // 40 KB staging
  int b = blockIdx.x, tid = threadIdx.x;
  int r0 = S[b * BLK];
  int r1 = S[(b + 1) * BLK];  // last bucket: S[L] = E
  int m = r1 - r0;
  for (int i = tid; i < 2048; i += 256) bins[i] = 0;
  __syncthreads();
  for (int i = r0 + tid; i < r1; i += 256) {
    u32 p = packed[i];
    int key = (int)((p >> 17) << 3) | (int)((p & 0x1FFFFu) >> 14);
    atomicAdd(&bins[key], 1);
  }
  __syncthreads();
  int s = 0;
#pragma unroll
  for (int u = 0; u < 8; ++u) s += bins[tid * 8 + u];  // s = degree of dl=tid
  scn[tid] = s;
  __syncthreads();
  for (int d = 1; d < 256; d <<= 1) {
    int t = (tid >= d) ? scn[tid - d] : 0;
    __syncthreads();
    scn[tid] += t;
    __syncthreads();
  }
  int base = scn[tid] - s;  // exclusive start of dl=tid's 8 bins
  int node = b * 256 + tid;
  if (node < n) {
    off[node] = r0 + base;
    dinv[node] = rsqrtf((float)(s + 1));  // +1 self-loop
  }
  if (b == NBk - 1 && tid == 0) off[n] = r1;
#pragma unroll
  for (int u = 0; u < 8; ++u) {
    int k = tid * 8 + u;
    cur[k] = base;
    base += bins[k];
  }
  __syncthreads();
  if (m <= CAP) {
    for (int i = r0 + tid; i < r1; i += 256) {
      u32 p = packed[i];
      int key = (int)((p >> 17) << 3) | (int)((p & 0x1FFFFu) >> 14);
      int pos = atomicAdd(&cur[key], 1);
      sbuf[pos] = p & 0x1FFFFu;
    }
    __syncthreads();
    for (int j = tid; j < m; j += 256)
      csr2[r0 + j] = sbuf[j];
  } else {
    // fallback: scattered global writes (statistically unreachable)
    for (int i = r0 + tid; i < r1; i += 256) {
      u32 p = packed[i];
      int key = (int)((p >> 17) << 3) | (int)((p & 0x1FFFFu) >> 14);
      int pos = atomicAdd(&cur[key], 1);
      csr2[r0 + pos] = p & 0x1FFFFu;
    }
  }
}

// ---------------- projection 1: h1p = bf16(dinv * (x @ W1^T))  [n,128]->[n,64] ----------------

__global__ void k_proj1(const float4* __restrict__ x4, const float* __restrict__ W1,
                        const float* __restrict__ dinv,
                        unsigned short* __restrict__ h1p, int n) {
  __shared__ float xs[16][IN_DIM];
  __shared__ float wt[IN_DIM][H1 + 1];
  int tid = threadIdx.x;
  int row0 = blockIdx.x * 16;

  for (int i = tid; i < (H1 * IN_DIM / 4); i += 256) {
    float4 w = ((const float4*)W1)[i];
    int o = (i * 4) / IN_DIM;
    int k = (i * 4) % IN_DIM;
    wt[k + 0][o] = w.x; wt[k + 1][o] = w.y; wt[k + 2][o] = w.z; wt[k + 3][o] = w.w;
  }
  for (int i = tid; i < 16 * IN_DIM / 4; i += 256) {
    int r = (i * 4) / IN_DIM, k = (i * 4) % IN_DIM;
    int row = row0 + r;
    if (row < n)
      *((float4*)&xs[r][k]) = x4[(size_t)row * (IN_DIM / 4) + k / 4];
  }
  __syncthreads();

  int o = tid & 63, rq = tid >> 6;
  float a0 = 0.f, a1 = 0.f, a2 = 0.f, a3 = 0.f;
  for (int k = 0; k < IN_DIM; ++k) {
    float w = wt[k][o];
    a0 += xs[rq * 4 + 0][k] * w;
    a1 += xs[rq * 4 + 1][k] * w;
    a2 += xs[rq * 4 + 2][k] * w;
    a3 += xs[rq * 4 + 3][k] * w;
  }
  int r = row0 + rq * 4;
  if (r + 0 < n) h1p[(size_t)(r + 0) * H1 + o] = f2b(a0 * dinv[r + 0]);
  if (r + 1 < n) h1p[(size_t)(r + 1) * H1 + o] = f2b(a1 * dinv[r + 1]);
  if (r + 2 < n) h1p[(size_t)(r + 2) * H1 + o] = f2b(a2 * dinv[r + 2]);
  if (r + 3 < n) h1p[(size_t)(r + 3) * H1 + o] = f2b(a3 * dinv[r + 3]);
}

// ---------------- G1 (R21): ordered-sweep layer-1 agg (reg acc) + relu + proj2 ----------------
// Block owns 64 consecutive dst nodes. 64 groups of 4 lanes; group cls owns
// node blockIdx*64+cls exclusively; accumulator in 16 VGPRs (no atomics).
// Edges per node contiguous and src-tile-ascending; all ~1563 uniform blocks
// co-resident => chip-wide moving src window => gathers L2-resident (R3 proof).

#define ACC16(u, v) do { \
    ac0  += bf_lo((u).x); ac1  += bf_hi((u).x); ac2  += bf_lo((u).y); ac3  += bf_hi((u).y); \
    ac4  += bf_lo((u).z); ac5  += bf_hi((u).z); ac6  += bf_lo((u).w); ac7  += bf_hi((u).w); \
    ac8  += bf_lo((v).x); ac9  += bf_hi((v).x); ac10 += bf_lo((v).y); ac11 += bf_hi((v).y); \
    ac12 += bf_lo((v).z); ac13 += bf_hi((v).z); ac14 += bf_lo((v).w); ac15 += bf_hi((v).w); } while (0)

__global__ __launch_bounds__(256, 6) void k_gagg1(
    const uint4* __restrict__ hp4,     // h1p rows: 128 B = 8 x uint4
    const float* __restrict__ dinv,
    const int* __restrict__ off, const u32* __restrict__ csr2,
    const float* __restrict__ b1, const float* __restrict__ W2,
    unsigned short* __restrict__ h2p, int n) {
  __shared__ float rows[64][H1];     // 16 KB: relu(out1) per node
  __shared__ float wt[H1][H2 + 1];   // 8.4 KB: W2 transposed
  __shared__ float b1s[H1];
  int tid = threadIdx.x;

  for (int i = tid; i < H2 * H1 / 4; i += 256) {
    float4 w = ((const float4*)W2)[i];
    int o = (i * 4) / H1, k = (i * 4) % H1;
    wt[k + 0][o] = w.x; wt[k + 1][o] = w.y; wt[k + 2][o] = w.z; wt[k + 3][o] = w.w;
  }
  if (tid < 16) ((float4*)b1s)[tid] = ((const float4*)b1)[tid];
  __syncthreads();

  int lane = tid & 63, wv = tid >> 6;
  int g = lane >> 2, j = lane & 3;   // 16 groups/wave, 4 lanes each; lane j reads 2x16B
  int cls = wv * 16 + g;             // 0..63: my node slot
  int node0 = blockIdx.x * 64;
  int mynode = node0 + cls;
  int valid = mynode < n;
  int nclamp = valid ? mynode : n - 1;

  // acc init = self term (table row has dinv[self] folded in)
  size_t selfb = (size_t)nclamp * 8;
  uint4 sv0 = hp4[selfb + j], sv1 = hp4[selfb + 4 + j];
  float ac0 = bf_lo(sv0.x), ac1 = bf_hi(sv0.x), ac2 = bf_lo(sv0.y), ac3 = bf_hi(sv0.y),
        ac4 = bf_lo(sv0.z), ac5 = bf_hi(sv0.z), ac6 = bf_lo(sv0.w), ac7 = bf_hi(sv0.w),
        ac8 = bf_lo(sv1.x), ac9 = bf_hi(sv1.x), ac10 = bf_lo(sv1.y), ac11 = bf_hi(sv1.y),
        ac12 = bf_lo(sv1.z), ac13 = bf_hi(sv1.z), ac14 = bf_lo(sv1.w), ac15 = bf_hi(sv1.w);

  int s0 = 0, s1 = 0;
  if (valid) { s0 = off[mynode]; s1 = off[mynode + 1]; }
  int i = s0;
  for (; i + 1 < s1; i += 2) {
    u32 p0 = csr2[i], p1 = csr2[i + 1];
    size_t sA = (size_t)p0 * 8;
    size_t sB = (size_t)p1 * 8;
    uint4 w0 = hp4[sA + j], w1 = hp4[sA + 4 + j];
    uint4 w2 = hp4[sB + j], w3 = hp4[sB + 4 + j];
    ACC16(w0, w1);
    ACC16(w2, w3);
  }
  if (i < s1) {
    u32 p0 = csr2[i];
    size_t sA = (size_t)p0 * 8;
    uint4 w0 = hp4[sA + j], w1 = hp4[sA + 4 + j];
    ACC16(w0, w1);
  }

  // epilogue E1: dinv scale + bias + relu -> rows (lane j owns cols 8j.. and 32+8j..)
  float d = dinv[nclamp];
  rows[cls][8 * j + 0] = fmaxf(ac0 * d + b1s[8 * j + 0], 0.f);
  rows[cls][8 * j + 1] = fmaxf(ac1 * d + b1s[8 * j + 1], 0.f);
  rows[cls][8 * j + 2] = fmaxf(ac2 * d + b1s[8 * j + 2], 0.f);
  rows[cls][8 * j + 3] = fmaxf(ac3 * d + b1s[8 * j + 3], 0.f);
  rows[cls][8 * j + 4] = fmaxf(ac4 * d + b1s[8 * j + 4], 0.f);
  rows[cls][8 * j + 5] = fmaxf(ac5 * d + b1s[8 * j + 5], 0.f);
  rows[cls][8 * j + 6] = fmaxf(ac6 * d + b1s[8 * j + 6], 0.f);
  rows[cls][8 * j + 7] = fmaxf(ac7 * d + b1s[8 * j + 7], 0.f);
  rows[cls][32 + 8 * j + 0] = fmaxf(ac8 * d + b1s[32 + 8 * j + 0], 0.f);
  rows[cls][32 + 8 * j + 1] = fmaxf(ac9 * d + b1s[32 + 8 * j + 1], 0.f);
  rows[cls][32 + 8 * j + 2] = fmaxf(ac10 * d + b1s[32 + 8 * j + 2], 0.f);
  rows[cls][32 + 8 * j + 3] = fmaxf(ac11 * d + b1s[32 + 8 * j + 3], 0.f);
  rows[cls][32 + 8 * j + 4] = fmaxf(ac12 * d + b1s[32 + 8 * j + 4], 0.f);
  rows[cls][32 + 8 * j + 5] = fmaxf(ac13 * d + b1s[32 + 8 * j + 5], 0.f);
  rows[cls][32 + 8 * j + 6] = fmaxf(ac14 * d + b1s[32 + 8 * j + 6], 0.f);
  rows[cls][32 + 8 * j + 7] = fmaxf(ac15 * d + b1s[32 + 8 * j + 7], 0.f);
  __syncthreads();

  // epilogue E2: proj2, 64 nodes x 32 outs = 2048 -> 8 per thread
#pragma unroll
  for (int u = 0; u < 8; ++u) {
    int idx = tid + u * 256;
    int nd = idx >> 5, o = idx & 31;
    int nodew = node0 + nd;
    if (nodew < n) {
      float a = 0.f;
#pragma unroll
      for (int k = 0; k < H1; ++k) a += rows[nd][k] * wt[k][o];
      h2p[(size_t)nodew * H2 + o] = f2b(a * dinv[nodew]);  // dinv folded for layer 2
    }
  }
}

// ---------------- G2 (R21): ordered-sweep layer-2 agg (reg acc) + gates + leaf ----------------

__global__ __launch_bounds__(256, 6) void k_gagg2(
    const uint4* __restrict__ hq4,     // h2p rows: 64 B = 4 x uint4
    const float* __restrict__ dinv,
    const int* __restrict__ off, const u32* __restrict__ csr2,
    const float* __restrict__ b2, const float* __restrict__ gate_w,
    const float* __restrict__ gate_b, const float* __restrict__ leaf_w,
    float* __restrict__ out, int n) {
  __shared__ float rowh[64][H2];     // 8 KB
  __shared__ float rowg[64][H2];     // 8 KB
  __shared__ float gwt[H2][H2 + 1];  // gate_w transposed
  __shared__ float lws[H2][NC + 1];
  __shared__ float b2s[H2];
  int tid = threadIdx.x;

  {
    float4 w = ((const float4*)gate_w)[tid];  // H2*H2/4 == 256
    int jj = (tid * 4) / H2, k = (tid * 4) % H2;
    gwt[k + 0][jj] = w.x; gwt[k + 1][jj] = w.y; gwt[k + 2][jj] = w.z; gwt[k + 3][jj] = w.w;
  }
  lws[tid >> 3][tid & 7] = leaf_w[tid];  // H2*NC == 256
  if (tid < 8) ((float4*)b2s)[tid] = ((const float4*)b2)[tid];
  __syncthreads();

  int lane = tid & 63, wv = tid >> 6;
  int g = lane >> 2, j = lane & 3;   // 16 groups of 4 lanes; lane j reads 16B
  int cls = wv * 16 + g;             // 0..63: my node slot
  int node0 = blockIdx.x * 64;
  int mynode = node0 + cls;
  int valid = mynode < n;
  int nclamp = valid ? mynode : n - 1;

  uint4 sv = hq4[(size_t)nclamp * 4 + j];   // self term
  float ac0 = bf_lo(sv.x), ac1 = bf_hi(sv.x), ac2 = bf_lo(sv.y), ac3 = bf_hi(sv.y),
        ac4 = bf_lo(sv.z), ac5 = bf_hi(sv.z), ac6 = bf_lo(sv.w), ac7 = bf_hi(sv.w);

  int s0 = 0, s1 = 0;
  if (valid) { s0 = off[mynode]; s1 = off[mynode + 1]; }
  int i = s0;
  for (; i + 1 < s1; i += 2) {
    u32 p0 = csr2[i], p1 = csr2[i + 1];
    uint4 w0 = hq4[(size_t)p0 * 4 + j];
    uint4 w1 = hq4[(size_t)p1 * 4 + j];
    ac0 += bf_lo(w0.x); ac1 += bf_hi(w0.x); ac2 += bf_lo(w0.y); ac3 += bf_hi(w0.y);
    ac4 += bf_lo(w0.z); ac5 += bf_hi(w0.z); ac6 += bf_lo(w0.w); ac7 += bf_hi(w0.w);
    ac0 += bf_lo(w1.x); ac1 += bf_hi(w1.x); ac2 += bf_lo(w1.y); ac3 += bf_hi(w1.y);
    ac4 += bf_lo(w1.z); ac5 += bf_hi(w1.z); ac6 += bf_lo(w1.w); ac7 += bf_hi(w1.w);
  }
  if (i < s1) {
    u32 p0 = csr2[i];
    uint4 w0 = hq4[(size_t)p0 * 4 + j];
    ac0 += bf_lo(w0.x); ac1 += bf_hi(w0.x); ac2 += bf_lo(w0.y); ac3 += bf_hi(w0.y);
    ac4 += bf_lo(w0.z); ac5 += bf_hi(w0.z); ac6 += bf_lo(w0.w); ac7 += bf_hi(w0.w);
  }

  // E1: dinv scale + b2 -> rowh (lane j owns cols 8j..8j+8)
  float d = dinv[nclamp];
  rowh[cls][8 * j + 0] = ac0 * d + b2s[8 * j + 0];
  rowh[cls][8 * j + 1] = ac1 * d + b2s[8 * j + 1];
  rowh[cls][8 * j + 2] = ac2 * d + b2s[8 * j + 2];
  rowh[cls][8 * j + 3] = ac3 * d + b2s[8 * j + 3];
  rowh[cls][8 * j + 4] = ac4 * d + b2s[8 * j + 4];
  rowh[cls][8 * j + 5] = ac5 * d + b2s[8 * j + 5];
  rowh[cls][8 * j + 6] = ac6 * d + b2s[8 * j + 6];
  rowh[cls][8 * j + 7] = ac7 * d + b2s[8 * j + 7];
  __syncthreads();

  // E2: gates, 64 nodes x 32 = 2048 -> 8 per thread
#pragma unroll
  for (int u = 0; u < 8; ++u) {
    int idx = tid + u * 256;
    int nd = idx >> 5, f = idx & 31;
    float gg = 0.f;
#pragma unroll
    for (int k = 0; k < H2; ++k) gg += rowh[nd][k] * gwt[k][f];
    rowg[nd][f] = 1.0f / (1.0f + __expf(-(gg + gate_b[f])));
  }
  __syncthreads();

  // E3: leaf, 64 nodes x 8 = 512 -> 2 per thread
#pragma unroll
  for (int u = 0; u < 2; ++u) {
    int idx = tid + u * 256;
    int nd = idx >> 3, c = idx & 7;
    int nodew = node0 + nd;
    if (nodew < n) {
      float a = 0.f;
#pragma unroll
      for (int k = 0; k < H2; ++k) a += rowg[nd][k] * lws[k][c];
      out[(size_t)nodew * NC + c] = a;
    }
  }
}

// ---------------- host ----------------

static inline size_t align256(size_t x) { return (x + 255) & ~(size_t)255; }

extern "C" void kernel_launch(void* const* d_in, const int* in_sizes, int n_in,
                              void* d_out, int out_size, void* d_ws, size_t ws_size,
                              hipStream_t stream) {
  const float* x  = (const float*)d_in[0];
  const int*   ei = (const int*)d_in[1];
  const float* W1 = (const float*)d_in[2];
  const float* b1 = (const float*)d_in[3];
  const float* W2 = (const float*)d_in[4];
  const float* b2 = (const float*)d_in[5];
  const float* gw = (const float*)d_in[6];
  const float* gb = (const float*)d_in[7];
  const float* lw = (const float*)d_in[8];
  float* out = (float*)d_out;

  int n = in_sizes[0] / IN_DIM;
  int E = in_sizes[1] / 2;
  const int* src  = ei;
  const int* dstp = ei + E;

  int NBk = (n + 255) >> 8;                    // buckets of 256 nodes
  int EPB = (E + BLK - 1) / BLK;               // edges per partition block
  int L   = NBk * BLK;                         // blockhist entries
  int nbs = (L + SCAN_CH - 1) / SCAN_CH;       // scan blocks

  // workspace layout: hot gather tables FIRST (256B-aligned; R17 straddle fix);
  // footprint identical to the R4/R5/R6 layout that ran clean.
  char* w = (char*)d_ws;
  unsigned short* h1p = (unsigned short*)w;  w += align256((size_t)n * H1 * 2);  // bf16 [n][64]
  unsigned short* h2p = (unsigned short*)w;  w += align256((size_t)n * H2 * 2);  // bf16 [n][32]
  u32* csr2   = (u32*)w;   w += align256((size_t)E * 4);
  u32* packed = (u32*)w;   w += align256((size_t)E * 4);
  int* bh     = (int*)w;   w += align256(((size_t)L + 1) * 4);
  int* S      = (int*)w;   w += align256(((size_t)L + 1) * 4);
  int* bsum   = (int*)w;   w += align256((size_t)nbs * 4);
  int* bbase  = (int*)w;   w += align256((size_t)nbs * 4);
  float* dinv = (float*)w; w += align256((size_t)n * 4);
  int* off    = (int*)w;   w += align256(((size_t)n + 1) * 4);

  int gnb = (n + 63) / 64;  // 64 nodes per gagg block

  k_hist<<<BLK, 256, 0, stream>>>(dstp, bh, E, EPB, NBk);
  k_gsc1<<<nbs, 256, 0, stream>>>(bh, bsum, L);
  k_gsc2<<<1, 256, 0, stream>>>(bsum, bbase, S, nbs, L);
  k_gsc3<<<nbs, 256, 0, stream>>>(bh, bbase, S, L);
  k_scatter<<<BLK, 256, 0, stream>>>(src, dstp, S, packed, E, EPB, NBk);
  k_build3<<<NBk, 256, 0, stream>>>(packed, S, csr2, off, dinv, n, NBk);

  k_proj1<<<(n + 15) / 16, 256, 0, stream>>>((const float4*)x, W1, dinv, h1p, n);
  k_gagg1<<<gnb, 256, 0, stream>>>((const uint4*)h1p, dinv, off, csr2, b1, W2, h2p, n);
  k_gagg2<<<gnb, 256, 0, stream>>>((const uint4*)h2p, dinv, off, csr2, b2, gw, gb, lw, out, n);
}